// Round 13
// baseline (829.694 us; speedup 1.0000x reference)
//
#include <hip/hip_runtime.h>
#include <stdint.h>

typedef unsigned short u16;
typedef unsigned int u32;
typedef __attribute__((ext_vector_type(8))) short short8;
typedef __attribute__((ext_vector_type(4))) float f32x4;
typedef __attribute__((ext_vector_type(2))) unsigned int u32x2;

#define TILE 4096       // edges per binA block
#define CSTG 6144       // csrB colstage capacity (mean bucket total ~4096)

__device__ __forceinline__ float b2f_bits(u32 bits){ union{u32 u; float f;} v; v.u=bits; return v.f; }
__device__ __forceinline__ float bf_lo(u32 w){ return b2f_bits(w<<16); }
__device__ __forceinline__ float bf_hi(u32 w){ return b2f_bits(w & 0xffff0000u); }
__device__ __forceinline__ u16 f2bf(float f){
  union{float f; u32 u;} v; v.f=f;
  return (u16)((v.u + 0x7fffu + ((v.u>>16)&1u))>>16);   // round-to-nearest-even
}

__device__ __forceinline__ int edge_at(const void* eiv, int is32, long long idx){
  return is32 ? ((const int*)eiv)[idx] : (int)((const long long*)eiv)[idx];
}
__device__ __forceinline__ int clampi(int v, int lo, int hi){
  return v < lo ? lo : (v > hi ? hi : v);
}

// ---------------- graph build ----------------

// pass A: per-tile LDS counting sort by coarse bucket (row>>7); DENSE per-tile flush.
// tile t's sorted pairs land at gbuf[t*TILE ..) (coalesced, single-writer lines);
// per-tile bucket boundaries go to baseAll[t*(nbuck+1) ..] (base[nbuck] = cnt).
// per-bucket totals accumulate into gcnt for the global start scan.
__global__ __launch_bounds__(256) void binA_k(const void* __restrict__ eiv,
                        int* __restrict__ gcnt, u32* __restrict__ gbuf, int* __restrict__ baseAll,
                        int E, int n, int nbuck){
  __shared__ int hist[1024];
  __shared__ int base[1024];
  __shared__ int cur[1024];
  __shared__ int wsum[256];
  __shared__ u32 stage[TILE];
  int t = threadIdx.x;
  // --- self-detect layout: any value >= n when read as int64 => data is int32
  {
    int lim = E/2 < 2048 ? E/2 : 2048;
    int bad = 0;
    const long long* e64 = (const long long*)eiv;
    for(int e=t; e<lim; e+=256){
      if((unsigned long long)e64[e] >= (unsigned long long)n) bad = 1;
    }
    wsum[t]=bad; __syncthreads();
    for(int off=128; off>0; off>>=1){ if(t<off) wsum[t] |= wsum[t+off]; __syncthreads(); }
  }
  int is32 = wsum[0];
  __syncthreads();
  long long e0 = (long long)blockIdx.x * TILE;
  int cnt = (int)((long long)E - e0 < TILE ? (long long)E - e0 : TILE);
  for(int i=t; i<nbuck; i+=256){ hist[i]=0; cur[i]=0; }
  __syncthreads();
  int eb[16]; u32 ep[16]; int ec=0;
  #pragma unroll
  for(int k=0;k<16;k++){
    int i = t + k*256;
    if(i<cnt){
      long long e = e0 + i;
      int r = clampi(edge_at(eiv,is32,e),0,n-1);
      int c = clampi(edge_at(eiv,is32,(long long)E+e),0,n-1);
      eb[ec] = r>>7;
      ep[ec] = ((u32)(r&127)<<17) | (u32)c;
      atomicAdd(&hist[eb[ec]],1);
      ec++;
    }
  }
  __syncthreads();
  int l[4]; int tot=0;
  #pragma unroll
  for(int j=0;j<4;j++){ int idx=t*4+j; l[j]=(idx<nbuck)?hist[idx]:0; tot+=l[j]; }
  wsum[t]=tot; __syncthreads();
  for(int off=1;off<256;off<<=1){
    int x = (t>=off)?wsum[t-off]:0;
    __syncthreads();
    wsum[t]+=x;
    __syncthreads();
  }
  int excl = wsum[t]-tot;
  #pragma unroll
  for(int j=0;j<4;j++){ int idx=t*4+j; if(idx<nbuck) base[idx]=excl; excl+=l[j]; }
  __syncthreads();
  for(int k=0;k<ec;k++){
    int b = eb[k];
    int slot = base[b] + atomicAdd(&cur[b],1);
    stage[slot] = ep[k];
  }
  __syncthreads();
  // dense coalesced flush of the whole sorted tile
  u32* dst = gbuf + (size_t)blockIdx.x * TILE;
  for(int i=t; i<cnt; i+=256) dst[i] = stage[i];
  // per-tile bucket boundary table (base[nbuck] == cnt sentinel)
  int* brow = baseAll + (size_t)blockIdx.x * (nbuck+1);
  for(int i=t; i<=nbuck; i+=256) brow[i] = (i<nbuck) ? base[i] : cnt;
  // per-bucket global totals
  for(int b=t; b<nbuck; b+=256){
    int c = hist[b];
    if(c>0) atomicAdd(&gcnt[b], c);
  }
}

// scan of per-bucket counts -> global bucket starts (one block)
__global__ __launch_bounds__(256) void scanG_k(const int* __restrict__ gcnt, int* __restrict__ gstart, int nbuck){
  __shared__ int sh[256];
  int t = threadIdx.x;
  int v[4]; int s=0;
  #pragma unroll
  for(int j=0;j<4;j++){
    int idx=t*4+j;
    v[j] = (idx<nbuck)?gcnt[idx]:0;
    s += v[j];
  }
  sh[t]=s; __syncthreads();
  for(int off=1;off<256;off<<=1){
    int x=(t>=off)?sh[t-off]:0;
    __syncthreads();
    sh[t]+=x;
    __syncthreads();
  }
  int excl = sh[t]-s;
  #pragma unroll
  for(int j=0;j<4;j++){ int idx=t*4+j; if(idx<nbuck) gstart[idx]=excl; excl+=v[j]; }
}

// pass B: per-bucket gather of tile runs (via baseAll) -> degree + local scan +
// deg/dinv/rs outputs + CSR materialization (dense contiguous writes)
__global__ __launch_bounds__(256) void csrB_k(const int* __restrict__ gstart,
                        const u32* __restrict__ gbuf, const int* __restrict__ baseAll,
                        int* __restrict__ deg, float* __restrict__ dinv,
                        int* __restrict__ rs, int* __restrict__ csr, int n, int nbuck, int ntile){
  __shared__ int h[128], lst[128], lcur[128], sc[128];
  __shared__ int colstage[CSTG];
  int b = blockIdx.x, t = threadIdx.x;
  if(t<128){ h[t]=0; lcur[t]=0; }
  __syncthreads();
  // pass 1: histogram of local rows over this bucket's runs in every tile
  for(int tt=t; tt<ntile; tt+=256){
    const int* brow = baseAll + (size_t)tt*(nbuck+1);
    int lo = brow[b], hi = brow[b+1];
    const u32* pp = gbuf + (size_t)tt*TILE;
    for(int i=lo;i<hi;i++) atomicAdd(&h[pp[i]>>17],1);
  }
  __syncthreads();
  int dv=0;
  if(t<128){ dv=h[t]; sc[t]=dv; }
  __syncthreads();
  for(int off=1;off<128;off<<=1){
    int x=(t>=off&&t<128)?sc[t-off]:0;
    __syncthreads();
    if(t<128) sc[t]+=x;
    __syncthreads();
  }
  int g0 = gstart[b];
  if(t<128){
    lst[t]=sc[t]-dv;
    int row=b*128+t;
    if(row<n){
      deg[row]=dv;
      dinv[row]=rsqrtf((float)(dv+1));   // +1: self loop
      rs[row]=g0+lst[t];
    }
  }
  __syncthreads();
  // pass 2: scatter into colstage (L2-warm re-read of the runs)
  for(int tt=t; tt<ntile; tt+=256){
    const int* brow = baseAll + (size_t)tt*(nbuck+1);
    int lo = brow[b], hi = brow[b+1];
    const u32* pp = gbuf + (size_t)tt*TILE;
    for(int i=lo;i<hi;i++){
      u32 pr = pp[i];
      int rl = pr>>17;
      int slot = lst[rl] + atomicAdd(&lcur[rl],1);
      if(slot < CSTG) colstage[slot] = (int)(pr & 0x1FFFFu);
    }
  }
  __syncthreads();
  int tot = sc[127]; if(tot > CSTG) tot = CSTG;
  for(int i=t;i<tot;i+=256) csr[g0+i]=colstage[i];
}

// ---------------- fused layer 0: wave-per-row propagate + K=3 GEMM (+ weight pack prologue) ----------------
__global__ __launch_bounds__(256) void gemm0w_k(const float* __restrict__ x, const int* __restrict__ csr,
                        const int* __restrict__ rs, const int* __restrict__ deg,
                        const float* __restrict__ dinv, const float* __restrict__ W0,
                        const float* __restrict__ b0, u16* __restrict__ h1,
                        const float* __restrict__ W1, const float* __restrict__ W2,
                        u16* __restrict__ W1p, u16* __restrict__ W2p, int n){
  // fold weight packing (W1,W2 -> MFMA B-fragment order) into the first 512 blocks
  if(blockIdx.x < 512){
    int bid = blockIdx.x;
    const float* W = (bid<256)? W1 : W2;
    u16* o = (bid<256)? W1p : W2p;
    int idx = (bid&255)*256 + threadIdx.x;
    int j  = idx & 7;
    int l  = (idx>>3) & 63;
    int ct = (idx>>9) & 15;
    int kk = idx>>13;
    int k  = kk*32 + (l>>4)*8 + j;
    int nn = ct*16 + (l&15);
    o[idx] = f2bf(W[k*256 + nn]);
  }
  int i = (blockIdx.x*256 + threadIdx.x) >> 6;
  if(i>=n) return;
  i = __builtin_amdgcn_readfirstlane(i);
  int lane = threadIdx.x & 63;
  int s = __builtin_amdgcn_readfirstlane(rs[i]);
  int d = __builtin_amdgcn_readfirstlane(deg[i]);
  float a0=0.f, a1=0.f, a2=0.f;
  for(int e=lane; e<d; e+=64){
    int c = csr[s+e];
    float w = dinv[c];
    a0 += w*x[c*3+0]; a1 += w*x[c*3+1]; a2 += w*x[c*3+2];
  }
  #pragma unroll
  for(int off=32; off>0; off>>=1){
    a0 += __shfl_xor(a0, off);
    a1 += __shfl_xor(a1, off);
    a2 += __shfl_xor(a2, off);
  }
  float di = dinv[i];
  float p0 = di*(a0 + di*x[i*3+0]);
  float p1 = di*(a1 + di*x[i*3+1]);
  float p2 = di*(a2 + di*x[i*3+2]);
  int c0 = lane*4;
  float v[4];
  #pragma unroll
  for(int j=0;j<4;j++){
    int col = c0 + j;
    float t = p0*W0[col] + p1*W0[256+col] + p2*W0[512+col] + b0[col];
    v[j] = fmaxf(t, 0.f) * di;
  }
  uint2 o;
  o.x = (u32)f2bf(v[0]) | ((u32)f2bf(v[1])<<16);
  o.y = (u32)f2bf(v[2]) | ((u32)f2bf(v[3])<<16);
  *(uint2*)(h1 + (size_t)i*256 + c0) = o;
}

// ---------------- propagate (256-wide bf16, one wave/row, 16 gathers in flight) ----------------
__global__ __launch_bounds__(256) void prop256_k(const u16* __restrict__ hin, u16* __restrict__ pout,
                          const int* __restrict__ csr, const int* __restrict__ rs,
                          const int* __restrict__ deg, const float* __restrict__ dinv, int n){
  int row = (blockIdx.x*256 + threadIdx.x) >> 6;
  if(row>=n) return;
  row = __builtin_amdgcn_readfirstlane(row);
  int lane = threadIdx.x & 63;
  int co = lane*4;
  const u16* hb = hin + co;
  uint2 sv = *(const uint2*)(hb + (size_t)row*256);
  float a0=bf_lo(sv.x), a1=bf_hi(sv.x), a2=bf_lo(sv.y), a3=bf_hi(sv.y);
  int s = __builtin_amdgcn_readfirstlane(rs[row]);
  int d = __builtin_amdgcn_readfirstlane(deg[row]);
  for(int base=0; base<d; base+=16){
    int cc[16]; u32 mk[16];
    #pragma unroll
    for(int j=0;j<16;j++){
      int ok = (base+j) < d;                 // wave-uniform
      cc[j] = csr[ok ? (s+base+j) : s];
      mk[j] = ok ? 0xffffffffu : 0u;
    }
    uint2 v[16];
    #pragma unroll
    for(int j=0;j<16;j++) v[j] = *(const uint2*)(hb + (size_t)cc[j]*256);
    #pragma unroll
    for(int j=0;j<16;j++){
      u32 xw = v[j].x & mk[j], yw = v[j].y & mk[j];
      a0 += bf_lo(xw); a1 += bf_hi(xw); a2 += bf_lo(yw); a3 += bf_hi(yw);
    }
  }
  float sc = dinv[row];
  u32x2 o;
  o.x = (u32)f2bf(a0*sc) | ((u32)f2bf(a1*sc)<<16);
  o.y = (u32)f2bf(a2*sc) | ((u32)f2bf(a3*sc)<<16);
  __builtin_nontemporal_store(o, (u32x2*)(pout + (size_t)row*256 + co));
}

// ---------------- GEMM (layer 1): out = dinv*relu(A@W+b) ----------------
__global__ __launch_bounds__(256) void gemm256_k(const u16* __restrict__ A, const u16* __restrict__ Bp,
                          const float* __restrict__ bias, const float* __restrict__ dinv,
                          u16* __restrict__ Out, int M){
  int wave = threadIdx.x>>6, lane = threadIdx.x&63;
  int rowbase = blockIdx.x*64 + wave*16;
  f32x4 acc[16];
  #pragma unroll
  for(int t=0;t<16;t++){ acc[t][0]=0.f; acc[t][1]=0.f; acc[t][2]=0.f; acc[t][3]=0.f; }
  const u16* Ap = A + (size_t)(rowbase + (lane&15))*256 + ((lane>>4)*8);
  const u16* Bl = Bp + (size_t)lane*8;
  #pragma unroll
  for(int kk=0; kk<8; kk++){
    short8 af = __builtin_nontemporal_load((const short8*)(Ap + kk*32));   // streaming, read-once
    const u16* bb = Bl + (size_t)kk*8192;
    #pragma unroll
    for(int t=0;t<16;t++){
      short8 bf = *(const short8*)(bb + t*512);
      acc[t] = __builtin_amdgcn_mfma_f32_16x16x32_bf16(af, bf, acc[t], 0, 0, 0);
    }
  }
  int r0 = rowbase + (lane>>4)*4;
  float dv[4]; bool ok[4];
  #pragma unroll
  for(int r=0;r<4;r++){ ok[r] = (r0+r) < M; dv[r] = ok[r] ? dinv[r0+r] : 0.f; }
  #pragma unroll
  for(int t=0;t<16;t++){
    int col = t*16 + (lane&15);
    float bc = bias[col];
    #pragma unroll
    for(int r=0;r<4;r++){
      if(ok[r]){
        float v = fmaxf(acc[t][r] + bc, 0.f) * dv[r];
        Out[(size_t)(r0+r)*256 + col] = f2bf(v);
      }
    }
  }
}

// ---------------- GEMM (layer 2) fused with W3 projection: qh = (dinv*relu(A@W+b)) @ W3 ----------------
__global__ __launch_bounds__(256) void gemm256w3_k(const u16* __restrict__ A, const u16* __restrict__ Bp,
                          const float* __restrict__ bias, const float* __restrict__ dinv,
                          const float* __restrict__ W3, float* __restrict__ qh, int M){
  __shared__ float w3s[768];
  for(int i=threadIdx.x; i<768; i+=256) w3s[i] = W3[i];
  __syncthreads();
  int wave = threadIdx.x>>6, lane = threadIdx.x&63;
  int rowbase = blockIdx.x*64 + wave*16;
  f32x4 acc[16];
  #pragma unroll
  for(int t=0;t<16;t++){ acc[t][0]=0.f; acc[t][1]=0.f; acc[t][2]=0.f; acc[t][3]=0.f; }
  const u16* Ap = A + (size_t)(rowbase + (lane&15))*256 + ((lane>>4)*8);
  const u16* Bl = Bp + (size_t)lane*8;
  #pragma unroll
  for(int kk=0; kk<8; kk++){
    short8 af = __builtin_nontemporal_load((const short8*)(Ap + kk*32));
    const u16* bb = Bl + (size_t)kk*8192;
    #pragma unroll
    for(int t=0;t<16;t++){
      short8 bf = *(const short8*)(bb + t*512);
      acc[t] = __builtin_amdgcn_mfma_f32_16x16x32_bf16(af, bf, acc[t], 0, 0, 0);
    }
  }
  int r0 = rowbase + (lane>>4)*4;
  int cl = lane & 15;
  float dv[4];
  #pragma unroll
  for(int r=0;r<4;r++) dv[r] = (r0+r) < M ? dinv[r0+r] : 0.f;   // 0 for pad rows -> contributes 0
  float q0[4]={0,0,0,0}, q1[4]={0,0,0,0}, q2[4]={0,0,0,0};
  #pragma unroll
  for(int t=0;t<16;t++){
    int col = t*16 + cl;
    float bc = bias[col];
    float w30=w3s[col*3+0], w31=w3s[col*3+1], w32=w3s[col*3+2];
    #pragma unroll
    for(int r=0;r<4;r++){
      float v = fmaxf(acc[t][r] + bc, 0.f) * dv[r];   // h3hat (unrounded)
      q0[r] += v*w30; q1[r] += v*w31; q2[r] += v*w32;
    }
  }
  #pragma unroll
  for(int off=1; off<16; off<<=1){
    #pragma unroll
    for(int r=0;r<4;r++){
      q0[r] += __shfl_xor(q0[r], off);
      q1[r] += __shfl_xor(q1[r], off);
      q2[r] += __shfl_xor(q2[r], off);
    }
  }
  if(cl==0){
    #pragma unroll
    for(int r=0;r<4;r++){
      int row = r0 + r;
      if(row < M){
        qh[row*3+0]=q0[r]; qh[row*3+1]=q1[r]; qh[row*3+2]=q2[r];
      }
    }
  }
}

// ---------------- final: wave-per-row edge-parallel 3-wide propagate + skip ----------------
__global__ __launch_bounds__(256) void final2_k(const float* __restrict__ qh, const float* __restrict__ x,
                        const int* __restrict__ csr, const int* __restrict__ rs,
                        const int* __restrict__ deg, const float* __restrict__ dinv,
                        const float* __restrict__ b3, const float* __restrict__ Wr,
                        const float* __restrict__ br, float* __restrict__ out, int n){
  int row = (blockIdx.x*256 + threadIdx.x) >> 6;
  if(row>=n) return;
  row = __builtin_amdgcn_readfirstlane(row);
  int lane = threadIdx.x & 63;
  int s = __builtin_amdgcn_readfirstlane(rs[row]);
  int d = __builtin_amdgcn_readfirstlane(deg[row]);
  float a0=0.f, a1=0.f, a2=0.f;
  for(int e=lane; e<d; e+=64){
    int c = csr[s+e];
    a0 += qh[c*3+0]; a1 += qh[c*3+1]; a2 += qh[c*3+2];
  }
  #pragma unroll
  for(int off=32; off>0; off>>=1){
    a0 += __shfl_xor(a0, off);
    a1 += __shfl_xor(a1, off);
    a2 += __shfl_xor(a2, off);
  }
  if(lane==0){
    float di = dinv[row];
    a0 = di*(a0 + qh[row*3+0]);
    a1 = di*(a1 + qh[row*3+1]);
    a2 = di*(a2 + qh[row*3+2]);
    float x0=x[row*3+0], x1=x[row*3+1], x2=x[row*3+2];
    out[row*3+0] = a0 + b3[0] + x0*Wr[0] + x1*Wr[3] + x2*Wr[6] + br[0];
    out[row*3+1] = a1 + b3[1] + x0*Wr[1] + x1*Wr[4] + x2*Wr[7] + br[1];
    out[row*3+2] = a2 + b3[2] + x0*Wr[2] + x1*Wr[5] + x2*Wr[8] + br[2];
  }
}

// ---------------- launch ----------------
extern "C" void kernel_launch(void* const* d_in, const int* in_sizes, int n_in,
                              void* d_out, int out_size, void* d_ws, size_t ws_size,
                              hipStream_t stream) {
  const float* x  = (const float*)d_in[0];
  const void*  ei = d_in[1];
  const float* W0 = (const float*)d_in[2];
  const float* b0 = (const float*)d_in[3];
  const float* W1 = (const float*)d_in[4];
  const float* b1 = (const float*)d_in[5];
  const float* W2 = (const float*)d_in[6];
  const float* b2 = (const float*)d_in[7];
  const float* W3 = (const float*)d_in[8];
  const float* b3 = (const float*)d_in[9];
  const float* Wr = (const float*)d_in[10];
  const float* br = (const float*)d_in[11];
  float* out = (float*)d_out;

  int n = in_sizes[0]/3;
  int E = in_sizes[1]/2;
  int nbuck = (n+127)>>7;              // 128 rows per bucket (<=1024)
  int ntile = (E+TILE-1)/TILE;
  int Mpad = ((n+63)/64)*64;

  char* p = (char*)d_ws;
  auto alloc = [&](size_t bytes)->char*{ char* r=p; p += (bytes+255)&~(size_t)255; return r; };
  int*   gcnt  = (int*)  alloc((size_t)nbuck*4);
  int*   gstart= (int*)  alloc((size_t)nbuck*4);
  int*   deg   = (int*)  alloc((size_t)n*4);
  float* dinv  = (float*)alloc((size_t)n*4);
  int*   rs    = (int*)  alloc((size_t)n*4);
  int*   csr   = (int*)  alloc((size_t)E*4);
  u16*   hA    = (u16*)  alloc((size_t)Mpad*512);
  u16*   hB    = (u16*)  alloc((size_t)Mpad*512);
  float* qh    = (float*)alloc((size_t)n*12);
  u16*   W1p   = (u16*)  alloc(65536*2);
  u16*   W2p   = (u16*)  alloc(65536*2);
  // gbuf (ntile*TILE*4 ~ 12.8MB) + baseAll (ntile*(nbuck+1)*4 ~ 2.45MB) alias hA (51.2MB):
  // both dead before gemm0w writes hA
  u32*   gbuf   = (u32*)hA;
  int*   baseAll= (int*)(hA + (size_t)16*1024*1024);   // 32MB offset in u16 units? no: byte math below
  baseAll = (int*)((char*)hA + (size_t)((size_t)ntile*TILE*4 + 255 & ~(size_t)255));

  int gA  = ntile;
  int gp  = (n*64+255)/256;            // one wave per row

  // graph build: tile-dense 2-pass counting sort
  hipMemsetAsync(gcnt, 0, (size_t)nbuck*4, stream);
  binA_k  <<<gA, 256, 0, stream>>>(ei, gcnt, gbuf, baseAll, E, n, nbuck);
  scanG_k <<<1, 256, 0, stream>>>(gcnt, gstart, nbuck);
  csrB_k  <<<nbuck, 256, 0, stream>>>(gstart, gbuf, baseAll, deg, dinv, rs, csr, n, nbuck, ntile);

  // layer 0 (fused wave-per-row propagate + K=3 GEMM + weight-pack prologue)
  gemm0w_k<<<gp, 256, 0, stream>>>(x, csr, rs, deg, dinv, W0, b0, hA, W1, W2, W1p, W2p, n);

  // layer 1
  prop256_k<<<gp, 256, 0, stream>>>(hA, hB, csr, rs, deg, dinv, n);
  gemm256_k<<<Mpad/64, 256, 0, stream>>>(hB, W1p, b1, dinv, hA, n);

  // layer 2 + W3 projection (fused; skips h3 materialization)
  prop256_k<<<gp, 256, 0, stream>>>(hA, hB, csr, rs, deg, dinv, n);
  gemm256w3_k<<<Mpad/64, 256, 0, stream>>>(hB, W2p, b2, dinv, W3, qh, n);

  // final propagate + skip
  final2_k<<<gp, 256, 0, stream>>>(qh, x, csr, rs, deg, dinv, b3, Wr, br, out, n);
}

// Round 15
// 795.514 us; speedup vs baseline: 1.0430x; 1.0430x over previous
//
#include <hip/hip_runtime.h>
#include <stdint.h>

typedef unsigned short u16;
typedef unsigned int u32;
typedef __attribute__((ext_vector_type(8))) short short8;
typedef __attribute__((ext_vector_type(4))) float f32x4;
typedef __attribute__((ext_vector_type(2))) unsigned int u32x2;

#define CAP 6144        // pairs per coarse bucket region (mean ~4096, +32 sigma margin)
#define TILE 4096       // edges per binA block

__device__ __forceinline__ float b2f_bits(u32 bits){ union{u32 u; float f;} v; v.u=bits; return v.f; }
__device__ __forceinline__ float bf_lo(u32 w){ return b2f_bits(w<<16); }
__device__ __forceinline__ float bf_hi(u32 w){ return b2f_bits(w & 0xffff0000u); }
__device__ __forceinline__ u16 f2bf(float f){
  union{float f; u32 u;} v; v.f=f;
  return (u16)((v.u + 0x7fffu + ((v.u>>16)&1u))>>16);   // round-to-nearest-even
}

__device__ __forceinline__ int edge_at(const void* eiv, int is32, long long idx){
  return is32 ? ((const int*)eiv)[idx] : (int)((const long long*)eiv)[idx];
}
__device__ __forceinline__ int clampi(int v, int lo, int hi){
  return v < lo ? lo : (v > hi ? hi : v);
}

// ---------------- graph build ----------------

// pass A: tile-level counting sort into coarse buckets (row>>7), pairs (r&127)<<17 | c
// self-detects int64-vs-int32 edge layout (no separate detect kernel)
__global__ __launch_bounds__(256) void binA_k(const void* __restrict__ eiv,
                        int* __restrict__ gcur, u32* __restrict__ gbuf, int E, int n, int nbuck){
  __shared__ int hist[1024];
  __shared__ int base[1024];
  __shared__ int cur[1024];
  __shared__ int wsum[256];
  __shared__ u32 stage[TILE];
  int t = threadIdx.x;
  // --- self-detect layout: any value >= n when read as int64 => data is int32
  {
    int lim = E/2 < 2048 ? E/2 : 2048;
    int bad = 0;
    const long long* e64 = (const long long*)eiv;
    for(int e=t; e<lim; e+=256){
      if((unsigned long long)e64[e] >= (unsigned long long)n) bad = 1;
    }
    wsum[t]=bad; __syncthreads();
    for(int off=128; off>0; off>>=1){ if(t<off) wsum[t] |= wsum[t+off]; __syncthreads(); }
  }
  int is32 = wsum[0];
  __syncthreads();
  long long e0 = (long long)blockIdx.x * TILE;
  int cnt = (int)((long long)E - e0 < TILE ? (long long)E - e0 : TILE);
  for(int i=t; i<nbuck; i+=256){ hist[i]=0; cur[i]=0; }
  __syncthreads();
  int eb[16]; u32 ep[16]; int ec=0;
  #pragma unroll
  for(int k=0;k<16;k++){
    int i = t + k*256;
    if(i<cnt){
      long long e = e0 + i;
      int r = clampi(edge_at(eiv,is32,e),0,n-1);
      int c = clampi(edge_at(eiv,is32,(long long)E+e),0,n-1);
      eb[ec] = r>>7;
      ep[ec] = ((u32)(r&127)<<17) | (u32)c;
      atomicAdd(&hist[eb[ec]],1);
      ec++;
    }
  }
  __syncthreads();
  int l[4]; int tot=0;
  #pragma unroll
  for(int j=0;j<4;j++){ int idx=t*4+j; l[j]=(idx<nbuck)?hist[idx]:0; tot+=l[j]; }
  wsum[t]=tot; __syncthreads();
  for(int off=1;off<256;off<<=1){
    int x = (t>=off)?wsum[t-off]:0;
    __syncthreads();
    wsum[t]+=x;
    __syncthreads();
  }
  int excl = wsum[t]-tot;
  #pragma unroll
  for(int j=0;j<4;j++){ int idx=t*4+j; if(idx<nbuck) base[idx]=excl; excl+=l[j]; }
  __syncthreads();
  for(int k=0;k<ec;k++){
    int b = eb[k];
    int slot = base[b] + atomicAdd(&cur[b],1);
    stage[slot] = ep[k];
  }
  __syncthreads();
  for(int b=t; b<nbuck; b+=256){
    int c = hist[b];
    if(c>0){
      int g = atomicAdd(&gcur[b], c);
      if(g > CAP) g = CAP;
      if(g + c > CAP) c = CAP - g;
      int src = base[b];
      u32* dst = gbuf + (size_t)b*CAP + g;
      for(int k=0;k<c;k++) dst[k] = stage[src+k];
    }
  }
}

// pass B (fused): self-computed bucket starts (LDS scan of gcnt) + per-bucket degree +
// local scan + deg/dinv/rs outputs + CSR materialization
__global__ __launch_bounds__(256) void csrB_k(const int* __restrict__ gcnt,
                        const u32* __restrict__ gbuf, int* __restrict__ deg, float* __restrict__ dinv,
                        int* __restrict__ rs, int* __restrict__ csr, int n, int nbuck){
  __shared__ int gsc[1024];
  __shared__ int wsum[256];
  __shared__ int h[128], lst[128], lcur[128], sc[128];
  __shared__ int colstage[CAP];
  int b = blockIdx.x, t = threadIdx.x;
  // global bucket-start scan (each block computes the full scan; 782 ints)
  int v[4]; int s=0;
  #pragma unroll
  for(int j=0;j<4;j++){
    int idx=t*4+j;
    int c = (idx<nbuck)?gcnt[idx]:0;
    if(c>CAP) c=CAP;
    v[j]=c; s+=c;
  }
  wsum[t]=s; __syncthreads();
  for(int off=1;off<256;off<<=1){
    int x=(t>=off)?wsum[t-off]:0;
    __syncthreads();
    wsum[t]+=x;
    __syncthreads();
  }
  int excl = wsum[t]-s;
  #pragma unroll
  for(int j=0;j<4;j++){ int idx=t*4+j; if(idx<nbuck) gsc[idx]=excl; excl+=v[j]; }
  if(t<128){ h[t]=0; lcur[t]=0; }
  __syncthreads();
  int g0 = gsc[b];
  int c = gcnt[b]; if(c>CAP) c=CAP;
  const u32* p = gbuf + (size_t)b*CAP;
  for(int i=t;i<c;i+=256) atomicAdd(&h[p[i]>>17],1);
  __syncthreads();
  int dv=0;
  if(t<128){ dv=h[t]; sc[t]=dv; }
  __syncthreads();
  for(int off=1;off<128;off<<=1){
    int x=(t>=off&&t<128)?sc[t-off]:0;
    __syncthreads();
    if(t<128) sc[t]+=x;
    __syncthreads();
  }
  if(t<128){
    lst[t]=sc[t]-dv;
    int row=b*128+t;
    if(row<n){
      deg[row]=dv;
      dinv[row]=rsqrtf((float)(dv+1));   // +1: self loop
      rs[row]=g0+lst[t];
    }
  }
  __syncthreads();
  for(int i=t;i<c;i+=256){
    u32 pr=p[i];
    int rl=pr>>17;
    int slot=lst[rl]+atomicAdd(&lcur[rl],1);
    if(slot<CAP) colstage[slot]=(int)(pr&0x1FFFFu);
  }
  __syncthreads();
  for(int i=t;i<c;i+=256) csr[g0+i]=colstage[i];
}

// ---------------- fused layer 0: wave-per-row propagate + K=3 GEMM (+ weight pack prologue) ----------------
__global__ __launch_bounds__(256) void gemm0w_k(const float* __restrict__ x, const int* __restrict__ csr,
                        const int* __restrict__ rs, const int* __restrict__ deg,
                        const float* __restrict__ dinv, const float* __restrict__ W0,
                        const float* __restrict__ b0, u16* __restrict__ h1,
                        const float* __restrict__ W1, const float* __restrict__ W2,
                        u16* __restrict__ W1p, u16* __restrict__ W2p, int n){
  // fold weight packing (W1,W2 -> MFMA B-fragment order) into the first 512 blocks
  if(blockIdx.x < 512){
    int bid = blockIdx.x;
    const float* W = (bid<256)? W1 : W2;
    u16* o = (bid<256)? W1p : W2p;
    int idx = (bid&255)*256 + threadIdx.x;
    int j  = idx & 7;
    int l  = (idx>>3) & 63;
    int ct = (idx>>9) & 15;
    int kk = idx>>13;
    int k  = kk*32 + (l>>4)*8 + j;
    int nn = ct*16 + (l&15);
    o[idx] = f2bf(W[k*256 + nn]);
  }
  int i = (blockIdx.x*256 + threadIdx.x) >> 6;
  if(i>=n) return;
  i = __builtin_amdgcn_readfirstlane(i);
  int lane = threadIdx.x & 63;
  int s = __builtin_amdgcn_readfirstlane(rs[i]);
  int d = __builtin_amdgcn_readfirstlane(deg[i]);
  float a0=0.f, a1=0.f, a2=0.f;
  for(int e=lane; e<d; e+=64){
    int c = csr[s+e];
    float w = dinv[c];
    a0 += w*x[c*3+0]; a1 += w*x[c*3+1]; a2 += w*x[c*3+2];
  }
  #pragma unroll
  for(int off=32; off>0; off>>=1){
    a0 += __shfl_xor(a0, off);
    a1 += __shfl_xor(a1, off);
    a2 += __shfl_xor(a2, off);
  }
  float di = dinv[i];
  float p0 = di*(a0 + di*x[i*3+0]);
  float p1 = di*(a1 + di*x[i*3+1]);
  float p2 = di*(a2 + di*x[i*3+2]);
  int c0 = lane*4;
  float v[4];
  #pragma unroll
  for(int j=0;j<4;j++){
    int col = c0 + j;
    float t = p0*W0[col] + p1*W0[256+col] + p2*W0[512+col] + b0[col];
    v[j] = fmaxf(t, 0.f) * di;
  }
  uint2 o;
  o.x = (u32)f2bf(v[0]) | ((u32)f2bf(v[1])<<16);
  o.y = (u32)f2bf(v[2]) | ((u32)f2bf(v[3])<<16);
  *(uint2*)(h1 + (size_t)i*256 + c0) = o;
}

// ---------------- propagate (256-wide bf16, one wave/row, 16 gathers in flight) ----------------
__global__ __launch_bounds__(256) void prop256_k(const u16* __restrict__ hin, u16* __restrict__ pout,
                          const int* __restrict__ csr, const int* __restrict__ rs,
                          const int* __restrict__ deg, const float* __restrict__ dinv, int n){
  int row = (blockIdx.x*256 + threadIdx.x) >> 6;
  if(row>=n) return;
  row = __builtin_amdgcn_readfirstlane(row);
  int lane = threadIdx.x & 63;
  int co = lane*4;
  const u16* hb = hin + co;
  uint2 sv = *(const uint2*)(hb + (size_t)row*256);
  float a0=bf_lo(sv.x), a1=bf_hi(sv.x), a2=bf_lo(sv.y), a3=bf_hi(sv.y);
  int s = __builtin_amdgcn_readfirstlane(rs[row]);
  int d = __builtin_amdgcn_readfirstlane(deg[row]);
  for(int base=0; base<d; base+=16){
    int cc[16]; u32 mk[16];
    #pragma unroll
    for(int j=0;j<16;j++){
      int ok = (base+j) < d;                 // wave-uniform
      cc[j] = csr[ok ? (s+base+j) : s];
      mk[j] = ok ? 0xffffffffu : 0u;
    }
    uint2 v[16];
    #pragma unroll
    for(int j=0;j<16;j++) v[j] = *(const uint2*)(hb + (size_t)cc[j]*256);
    #pragma unroll
    for(int j=0;j<16;j++){
      u32 xw = v[j].x & mk[j], yw = v[j].y & mk[j];
      a0 += bf_lo(xw); a1 += bf_hi(xw); a2 += bf_lo(yw); a3 += bf_hi(yw);
    }
  }
  float sc = dinv[row];
  u32x2 o;
  o.x = (u32)f2bf(a0*sc) | ((u32)f2bf(a1*sc)<<16);
  o.y = (u32)f2bf(a2*sc) | ((u32)f2bf(a3*sc)<<16);
  __builtin_nontemporal_store(o, (u32x2*)(pout + (size_t)row*256 + co));
}

// ---------------- GEMM (layer 1): out = dinv*relu(A@W+b) ----------------
__global__ __launch_bounds__(256) void gemm256_k(const u16* __restrict__ A, const u16* __restrict__ Bp,
                          const float* __restrict__ bias, const float* __restrict__ dinv,
                          u16* __restrict__ Out, int M){
  int wave = threadIdx.x>>6, lane = threadIdx.x&63;
  int rowbase = blockIdx.x*64 + wave*16;
  f32x4 acc[16];
  #pragma unroll
  for(int t=0;t<16;t++){ acc[t][0]=0.f; acc[t][1]=0.f; acc[t][2]=0.f; acc[t][3]=0.f; }
  const u16* Ap = A + (size_t)(rowbase + (lane&15))*256 + ((lane>>4)*8);
  const u16* Bl = Bp + (size_t)lane*8;
  #pragma unroll
  for(int kk=0; kk<8; kk++){
    short8 af = __builtin_nontemporal_load((const short8*)(Ap + kk*32));   // streaming, read-once
    const u16* bb = Bl + (size_t)kk*8192;
    #pragma unroll
    for(int t=0;t<16;t++){
      short8 bf = *(const short8*)(bb + t*512);
      acc[t] = __builtin_amdgcn_mfma_f32_16x16x32_bf16(af, bf, acc[t], 0, 0, 0);
    }
  }
  int r0 = rowbase + (lane>>4)*4;
  float dv[4]; bool ok[4];
  #pragma unroll
  for(int r=0;r<4;r++){ ok[r] = (r0+r) < M; dv[r] = ok[r] ? dinv[r0+r] : 0.f; }
  #pragma unroll
  for(int t=0;t<16;t++){
    int col = t*16 + (lane&15);
    float bc = bias[col];
    #pragma unroll
    for(int r=0;r<4;r++){
      if(ok[r]){
        float v = fmaxf(acc[t][r] + bc, 0.f) * dv[r];
        Out[(size_t)(r0+r)*256 + col] = f2bf(v);
      }
    }
  }
}

// ---------------- GEMM (layer 2) fused with W3 projection: qh = (dinv*relu(A@W+b)) @ W3 ----------------
__global__ __launch_bounds__(256) void gemm256w3_k(const u16* __restrict__ A, const u16* __restrict__ Bp,
                          const float* __restrict__ bias, const float* __restrict__ dinv,
                          const float* __restrict__ W3, float* __restrict__ qh, int M){
  __shared__ float w3s[768];
  for(int i=threadIdx.x; i<768; i+=256) w3s[i] = W3[i];
  __syncthreads();
  int wave = threadIdx.x>>6, lane = threadIdx.x&63;
  int rowbase = blockIdx.x*64 + wave*16;
  f32x4 acc[16];
  #pragma unroll
  for(int t=0;t<16;t++){ acc[t][0]=0.f; acc[t][1]=0.f; acc[t][2]=0.f; acc[t][3]=0.f; }
  const u16* Ap = A + (size_t)(rowbase + (lane&15))*256 + ((lane>>4)*8);
  const u16* Bl = Bp + (size_t)lane*8;
  #pragma unroll
  for(int kk=0; kk<8; kk++){
    short8 af = __builtin_nontemporal_load((const short8*)(Ap + kk*32));
    const u16* bb = Bl + (size_t)kk*8192;
    #pragma unroll
    for(int t=0;t<16;t++){
      short8 bf = *(const short8*)(bb + t*512);
      acc[t] = __builtin_amdgcn_mfma_f32_16x16x32_bf16(af, bf, acc[t], 0, 0, 0);
    }
  }
  int r0 = rowbase + (lane>>4)*4;
  int cl = lane & 15;
  float dv[4];
  #pragma unroll
  for(int r=0;r<4;r++) dv[r] = (r0+r) < M ? dinv[r0+r] : 0.f;   // 0 for pad rows -> contributes 0
  float q0[4]={0,0,0,0}, q1[4]={0,0,0,0}, q2[4]={0,0,0,0};
  #pragma unroll
  for(int t=0;t<16;t++){
    int col = t*16 + cl;
    float bc = bias[col];
    float w30=w3s[col*3+0], w31=w3s[col*3+1], w32=w3s[col*3+2];
    #pragma unroll
    for(int r=0;r<4;r++){
      float v = fmaxf(acc[t][r] + bc, 0.f) * dv[r];   // h3hat (unrounded)
      q0[r] += v*w30; q1[r] += v*w31; q2[r] += v*w32;
    }
  }
  #pragma unroll
  for(int off=1; off<16; off<<=1){
    #pragma unroll
    for(int r=0;r<4;r++){
      q0[r] += __shfl_xor(q0[r], off);
      q1[r] += __shfl_xor(q1[r], off);
      q2[r] += __shfl_xor(q2[r], off);
    }
  }
  if(cl==0){
    #pragma unroll
    for(int r=0;r<4;r++){
      int row = r0 + r;
      if(row < M){
        qh[row*3+0]=q0[r]; qh[row*3+1]=q1[r]; qh[row*3+2]=q2[r];
      }
    }
  }
}

// ---------------- final: wave-per-row edge-parallel 3-wide propagate + skip ----------------
__global__ __launch_bounds__(256) void final2_k(const float* __restrict__ qh, const float* __restrict__ x,
                        const int* __restrict__ csr, const int* __restrict__ rs,
                        const int* __restrict__ deg, const float* __restrict__ dinv,
                        const float* __restrict__ b3, const float* __restrict__ Wr,
                        const float* __restrict__ br, float* __restrict__ out, int n){
  int row = (blockIdx.x*256 + threadIdx.x) >> 6;
  if(row>=n) return;
  row = __builtin_amdgcn_readfirstlane(row);
  int lane = threadIdx.x & 63;
  int s = __builtin_amdgcn_readfirstlane(rs[row]);
  int d = __builtin_amdgcn_readfirstlane(deg[row]);
  float a0=0.f, a1=0.f, a2=0.f;
  for(int e=lane; e<d; e+=64){
    int c = csr[s+e];
    a0 += qh[c*3+0]; a1 += qh[c*3+1]; a2 += qh[c*3+2];
  }
  #pragma unroll
  for(int off=32; off>0; off>>=1){
    a0 += __shfl_xor(a0, off);
    a1 += __shfl_xor(a1, off);
    a2 += __shfl_xor(a2, off);
  }
  if(lane==0){
    float di = dinv[row];
    a0 = di*(a0 + qh[row*3+0]);
    a1 = di*(a1 + qh[row*3+1]);
    a2 = di*(a2 + qh[row*3+2]);
    float x0=x[row*3+0], x1=x[row*3+1], x2=x[row*3+2];
    out[row*3+0] = a0 + b3[0] + x0*Wr[0] + x1*Wr[3] + x2*Wr[6] + br[0];
    out[row*3+1] = a1 + b3[1] + x0*Wr[1] + x1*Wr[4] + x2*Wr[7] + br[1];
    out[row*3+2] = a2 + b3[2] + x0*Wr[2] + x1*Wr[5] + x2*Wr[8] + br[2];
  }
}

// ---------------- launch ----------------
extern "C" void kernel_launch(void* const* d_in, const int* in_sizes, int n_in,
                              void* d_out, int out_size, void* d_ws, size_t ws_size,
                              hipStream_t stream) {
  const float* x  = (const float*)d_in[0];
  const void*  ei = d_in[1];
  const float* W0 = (const float*)d_in[2];
  const float* b0 = (const float*)d_in[3];
  const float* W1 = (const float*)d_in[4];
  const float* b1 = (const float*)d_in[5];
  const float* W2 = (const float*)d_in[6];
  const float* b2 = (const float*)d_in[7];
  const float* W3 = (const float*)d_in[8];
  const float* b3 = (const float*)d_in[9];
  const float* Wr = (const float*)d_in[10];
  const float* br = (const float*)d_in[11];
  float* out = (float*)d_out;

  int n = in_sizes[0]/3;
  int E = in_sizes[1]/2;
  int nbuck = (n+127)>>7;              // 128 rows per bucket (<=1024)
  int Mpad = ((n+63)/64)*64;

  char* p = (char*)d_ws;
  auto alloc = [&](size_t bytes)->char*{ char* r=p; p += (bytes+255)&~(size_t)255; return r; };
  int*   gcur  = (int*)  alloc((size_t)nbuck*4);
  int*   deg   = (int*)  alloc((size_t)n*4);
  float* dinv  = (float*)alloc((size_t)n*4);
  int*   rs    = (int*)  alloc((size_t)n*4);
  int*   csr   = (int*)  alloc((size_t)E*4);
  u16*   hA    = (u16*)  alloc((size_t)Mpad*512);
  u16*   hB    = (u16*)  alloc((size_t)Mpad*512);
  float* qh    = (float*)alloc((size_t)n*12);
  u16*   W1p   = (u16*)  alloc(65536*2);
  u16*   W2p   = (u16*)  alloc(65536*2);
  // gbuf (nbuck*CAP*4 ~ 19.2MB) aliases hA (51.2MB): dead before gemm0w writes hA
  u32*   gbuf  = (u32*)hA;

  int gA  = (E+TILE-1)/TILE;
  int gp  = (n*64+255)/256;            // one wave per row

  // graph build: 2-pass LDS-staged counting sort (self-detecting, self-scanning)
  hipMemsetAsync(gcur, 0, (size_t)nbuck*4, stream);
  binA_k  <<<gA, 256, 0, stream>>>(ei, gcur, gbuf, E, n, nbuck);
  csrB_k  <<<nbuck, 256, 0, stream>>>(gcur, gbuf, deg, dinv, rs, csr, n, nbuck);

  // layer 0 (fused wave-per-row propagate + K=3 GEMM + weight-pack prologue)
  gemm0w_k<<<gp, 256, 0, stream>>>(x, csr, rs, deg, dinv, W0, b0, hA, W1, W2, W1p, W2p, n);

  // layer 1
  prop256_k<<<gp, 256, 0, stream>>>(hA, hB, csr, rs, deg, dinv, n);
  gemm256_k<<<Mpad/64, 256, 0, stream>>>(hB, W1p, b1, dinv, hA, n);

  // layer 2 + W3 projection (fused; skips h3 materialization)
  prop256_k<<<gp, 256, 0, stream>>>(hA, hB, csr, rs, deg, dinv, n);
  gemm256w3_k<<<Mpad/64, 256, 0, stream>>>(hB, W2p, b2, dinv, W3, qh, n);

  // final propagate + skip
  final2_k<<<gp, 256, 0, stream>>>(qh, x, csr, rs, deg, dinv, b3, Wr, br, out, n);
}